// Round 1
// baseline (706.335 us; speedup 1.0000x reference)
//
#include <hip/hip_runtime.h>

// MLPPredictor: score[e] = relu(h[src[e]]@W1u + h[dst[e]]@W1v + b1) @ W2 + b2
// Stage A: PQ = h @ [W1u | W1v] via bf16 MFMA (memory-bound GEMM, b1 folded
//          into the Q half).  PQ bf16 [n_nodes][256] in d_ws.
// Stage B: per-edge gather directly into MFMA A-fragments (no LDS staging,
//          no loop barriers), hid = relu(P[src]+Q'[dst]), then (16x96) MFMA
//          against W2 fragments; non-temporal out stores to keep PQ in cache.

typedef short bf16x8 __attribute__((ext_vector_type(8)));   // 8 bf16 = 4 VGPR
typedef float f32x4 __attribute__((ext_vector_type(4)));

#define DIM 128
#define C_OUT 86
#define NPAD 96      // 86 padded to 6 x 16 MFMA tiles
#define HSTRIDE 136  // bf16 row stride for W2T LDS (2-way bank alias = free)

__device__ __forceinline__ float bf2f(unsigned short u) {
    unsigned int x = ((unsigned int)u) << 16;
    float f;
    __builtin_memcpy(&f, &x, 4);
    return f;
}
__device__ __forceinline__ unsigned short f2bf(float f) {
    unsigned int x;
    __builtin_memcpy(&x, &f, 4);
    x = x + 0x7fffu + ((x >> 16) & 1u);   // round-to-nearest-even
    return (unsigned short)(x >> 16);
}

// ---------------- Stage A: PQ[n][0:128]=h[n]@W1u, PQ[n][128:256]=h[n]@W1v+b1
// bf16 MFMA GEMM. Block = 256 thr (4 waves), tile M=64, N=256 (wave = 64-col
// quadrant), K=128 one-shot. A staged in LDS bf16 with XOR-swizzle; B frags
// loaded per-lane straight from W1 (L2-hot, 131 KB shared by all blocks).
__global__ __launch_bounds__(256) void node_gemm_kernel(
    const float* __restrict__ h, const float* __restrict__ W1,
    const float* __restrict__ b1, unsigned short* __restrict__ PQ, int n_nodes)
{
    __shared__ unsigned short Abf[64 * 128];   // 16 KB, XOR-swizzled 16B units

    const int t = threadIdx.x;
    const int m0 = blockIdx.x * 64;
    const int lane = t & 63;
    const int wv = t >> 6;        // wave -> 64-col quadrant of N=256
    const int m = lane & 15;
    const int quad = lane >> 4;

    // B fragments: B[k][n], n = wv*64 + nt*16 + m, k = kt*32 + quad*8 + j
    // n<128 -> W1u col n (stride 128); n>=128 -> W1v col n-128
    bf16x8 Bf[4][4];
    float b1v[4];
#pragma unroll
    for (int nt = 0; nt < 4; ++nt) {
        int n = wv * 64 + nt * 16 + m;
        const float* colp = (n < DIM) ? (W1 + n) : (W1 + DIM * DIM + (n - DIM));
        b1v[nt] = (n >= DIM) ? b1[n - DIM] : 0.f;   // fold b1 into Q half
#pragma unroll
        for (int kt = 0; kt < 4; ++kt) {
            bf16x8 f;
#pragma unroll
            for (int j = 0; j < 8; ++j)
                f[j] = (short)f2bf(colp[(kt * 32 + quad * 8 + j) * DIM]);
            Bf[nt][kt] = f;
        }
    }

    // stage A tile: 64 rows x 128 cols f32 -> bf16 LDS, 16B chunks,
    // byte ^= ((row&7)<<4) swizzle -> conflict-free ds_read_b128 below
#pragma unroll
    for (int it = 0; it < 4; ++it) {
        int i = t + it * 256;          // 1024 chunks of 16B
        int r = i >> 4;
        int c = i & 15;
        int gr = m0 + r;
        float4 v0 = make_float4(0.f, 0.f, 0.f, 0.f), v1 = v0;
        if (gr < n_nodes) {
            const float* hp = h + (size_t)gr * DIM + c * 8;
            v0 = *(const float4*)hp;
            v1 = *(const float4*)(hp + 4);
        }
        bf16x8 o;
        o[0] = (short)f2bf(v0.x); o[1] = (short)f2bf(v0.y);
        o[2] = (short)f2bf(v0.z); o[3] = (short)f2bf(v0.w);
        o[4] = (short)f2bf(v1.x); o[5] = (short)f2bf(v1.y);
        o[6] = (short)f2bf(v1.z); o[7] = (short)f2bf(v1.w);
        int byteoff = r * 256 + ((c * 16) ^ ((r & 7) << 4));
        *(bf16x8*)((char*)Abf + byteoff) = o;
    }
    __syncthreads();

#pragma unroll
    for (int mt = 0; mt < 4; ++mt) {
        bf16x8 af[4];
        int row = mt * 16 + m;
        int rs = row * 256;
        int sw = (row & 7) << 4;
#pragma unroll
        for (int kt = 0; kt < 4; ++kt) {
            int byteoff = rs + (((kt * 4 + quad) * 16) ^ sw);
            af[kt] = *(const bf16x8*)((const char*)Abf + byteoff);
        }
#pragma unroll
        for (int nt = 0; nt < 4; ++nt) {
            f32x4 acc = {0.f, 0.f, 0.f, 0.f};
#pragma unroll
            for (int kt = 0; kt < 4; ++kt)
                acc = __builtin_amdgcn_mfma_f32_16x16x32_bf16(af[kt], Bf[nt][kt], acc, 0, 0, 0);
            int nn = wv * 64 + nt * 16 + m;   // C/D: col = lane&15, row = quad*4+r
#pragma unroll
            for (int r = 0; r < 4; ++r) {
                int gm = m0 + mt * 16 + quad * 4 + r;
                if (gm < n_nodes)
                    PQ[(size_t)gm * 256 + nn] = f2bf(acc[r] + b1v[nt]);
            }
        }
    }
}

// ---------------- Stage B: per-edge MLP, register-direct gather ---------------
// Wave-independent: each wave owns 16 edges/iter. Lane (m,quad) gathers its own
// A-fragment slices of P[src[eb+m]] / Q'[dst[eb+m]] (16B each, 4 lanes cover a
// contiguous 64B per edge), relu-adds in registers, 24 MFMAs vs W2 B-frags.
__global__ __launch_bounds__(256) void edge_mlp_kernel(
    const unsigned short* __restrict__ PQ,
    const float* __restrict__ W2,
    const float* __restrict__ b2,
    const int* __restrict__ src,
    const int* __restrict__ dst,
    float* __restrict__ out,
    int n_edges)
{
    __shared__ unsigned short W2T[NPAD * HSTRIDE];   // W2 transposed [n][k], bf16
    __shared__ float b2s[NPAD];

    const int t = threadIdx.x;
    for (int i = t; i < NPAD * DIM; i += 256) {      // setup: W2 -> W2T (bf16)
        int n = i >> 7;
        int k = i & 127;
        float v = (n < C_OUT) ? W2[(size_t)k * C_OUT + n] : 0.f;
        W2T[n * HSTRIDE + k] = f2bf(v);
    }
    if (t < NPAD) b2s[t] = (t < C_OUT) ? b2[t] : 0.f;
    __syncthreads();

    const int lane = t & 63;
    const int wv = t >> 6;
    const int m = lane & 15;
    const int quad = lane >> 4;

    // B fragments: B[k][n], n = nt*16+m, k = kt*32 + quad*8 + j
    bf16x8 Bfrag[6][4];
#pragma unroll
    for (int nt = 0; nt < 6; ++nt)
#pragma unroll
        for (int kt = 0; kt < 4; ++kt)
            Bfrag[nt][kt] = *(const bf16x8*)&W2T[(nt * 16 + m) * HSTRIDE + kt * 32 + quad * 8];

    const int gw = blockIdx.x * 4 + wv;       // global wave id
    const int gstride = gridDim.x * 4 * 16;   // edges per grid sweep

    for (int eb = gw * 16; eb < n_edges; eb += gstride) {
        int edge = eb + m;
        bool ev = edge < n_edges;
        int s = ev ? src[edge] : 0;
        int d = ev ? dst[edge] : 0;
        const bf16x8* Pr = (const bf16x8*)(PQ + (size_t)s * 256);        // P half
        const bf16x8* Qr = (const bf16x8*)(PQ + (size_t)d * 256 + 128);  // Q' half
        bf16x8 pf[4], qf[4];
#pragma unroll
        for (int kt = 0; kt < 4; ++kt) {
            pf[kt] = Pr[kt * 4 + quad];       // 16B at k = kt*32 + quad*8
            qf[kt] = Qr[kt * 4 + quad];
        }
        // hid A-frag in registers: relu(P + Q')  (b1 already folded into Q')
        bf16x8 af[4];
#pragma unroll
        for (int kt = 0; kt < 4; ++kt) {
#pragma unroll
            for (int j = 0; j < 8; ++j) {
                float x = bf2f((unsigned short)pf[kt][j]) + bf2f((unsigned short)qf[kt][j]);
                af[kt][j] = (short)f2bf(fmaxf(x, 0.f));
            }
        }
#pragma unroll
        for (int nt = 0; nt < 6; ++nt) {
            f32x4 acc = {0.f, 0.f, 0.f, 0.f};
#pragma unroll
            for (int kt = 0; kt < 4; ++kt)
                acc = __builtin_amdgcn_mfma_f32_16x16x32_bf16(af[kt], Bfrag[nt][kt], acc, 0, 0, 0);
            int col = nt * 16 + m;   // C/D: col = lane&15, row = quad*4 + reg
            if (col < C_OUT) {
                float bias = b2s[col];
                int ebase = eb + quad * 4;
#pragma unroll
                for (int r = 0; r < 4; ++r) {
                    int e2 = ebase + r;
                    if (e2 < n_edges)
                        __builtin_nontemporal_store(acc[r] + bias,
                                                    &out[(size_t)e2 * C_OUT + col]);
                }
            }
        }
    }
}

extern "C" void kernel_launch(void* const* d_in, const int* in_sizes, int n_in,
                              void* d_out, int out_size, void* d_ws, size_t ws_size,
                              hipStream_t stream) {
    const float* h  = (const float*)d_in[0];
    const float* W1 = (const float*)d_in[1];
    const float* b1 = (const float*)d_in[2];
    const float* W2 = (const float*)d_in[3];
    const float* b2 = (const float*)d_in[4];
    const int* src  = (const int*)d_in[5];
    const int* dst  = (const int*)d_in[6];
    float* out = (float*)d_out;
    const int n_nodes = in_sizes[0] / DIM;      // 100000
    const int n_edges = in_sizes[5];            // 1000000
    unsigned short* PQ = (unsigned short*)d_ws; // 100000*256 bf16 = 51.2 MB

    node_gemm_kernel<<<dim3((n_nodes + 63) / 64), 256, 0, stream>>>(h, W1, b1, PQ, n_nodes);
    // 6 blocks/CU (26.5 KB LDS) * 256 CU = 1536 fully-resident blocks
    edge_mlp_kernel<<<dim3(1536), 256, 0, stream>>>(PQ, W2, b2, src, dst, out, n_edges);
}

// Round 2
// 517.824 us; speedup vs baseline: 1.3640x; 1.3640x over previous
//
#include <hip/hip_runtime.h>

// MLPPredictor: score[e] = relu(h[src[e]]@W1u + h[dst[e]]@W1v + b1) @ W2 + b2
// Kernel 0 (setup): W1 -> W1T bf16 [256][128] col-major-by-output; W2 -> W2T
//                   bf16 [96][128]. Both L2-hot, enable vector B-frag loads.
// Kernel 1 (stage A): PQ = h @ [W1u | W1v] via bf16 MFMA, b1 folded into the
//                   Q half. LDS-staged epilogue -> 16B PQ stores.
// Kernel 2 (stage B): 64-edge chunks staged in LDS (XOR-swizzled), 24 MFMAs
//                   per wave vs register-resident W2 frags, plain fp32 stores.

typedef short bf16x8 __attribute__((ext_vector_type(8)));   // 8 bf16 = 4 VGPR
typedef float f32x4 __attribute__((ext_vector_type(4)));

#define DIM 128
#define C_OUT 86
#define NPAD 96      // 86 padded to 6 x 16 MFMA tiles

__device__ __forceinline__ float bf2f(unsigned short u) {
    unsigned int x = ((unsigned int)u) << 16;
    float f;
    __builtin_memcpy(&f, &x, 4);
    return f;
}
__device__ __forceinline__ unsigned short f2bf(float f) {
    unsigned int x;
    __builtin_memcpy(&x, &f, 4);
    x = x + 0x7fffu + ((x >> 16) & 1u);   // round-to-nearest-even
    return (unsigned short)(x >> 16);
}

// ---------------- Kernel 0: weight transposes (runs once, ~3 us) -------------
// W1T[j][k] = W1[k][j] (j<128, W1u) | W1[128+k][j-128] (W1v).  W2T[n][k]=W2[k][n].
__global__ __launch_bounds__(256) void setup_kernel(
    const float* __restrict__ W1, const float* __restrict__ W2,
    unsigned short* __restrict__ W1T, unsigned short* __restrict__ W2T)
{
    int id = blockIdx.x * 256 + threadIdx.x;
    if (id < 256 * DIM) {
        int j = id >> 7, k = id & 127;
        float v = (j < DIM) ? W1[(size_t)k * DIM + j]
                            : W1[(size_t)(DIM + k) * DIM + (j - DIM)];
        W1T[id] = f2bf(v);
    } else {
        id -= 256 * DIM;
        if (id < NPAD * DIM) {
            int n = id >> 7, k = id & 127;
            float v = (n < C_OUT) ? W2[(size_t)k * C_OUT + n] : 0.f;
            W2T[id] = f2bf(v);
        }
    }
}

// ---------------- Stage A: PQ[n][0:128]=h@W1u, PQ[n][128:256]=h@W1v+b1 -------
// Block = 256 thr (4 waves), tile M=64, wave = 64-col quadrant of N=256, K=128.
__global__ __launch_bounds__(256) void node_gemm_kernel(
    const float* __restrict__ h, const unsigned short* __restrict__ W1T,
    const float* __restrict__ b1, unsigned short* __restrict__ PQ, int n_nodes)
{
    __shared__ unsigned short Abf[64 * 128];   // 16 KB, XOR-swizzled 16B units
    __shared__ unsigned short Cst[64 * 256];   // 32 KB epilogue staging

    const int t = threadIdx.x;
    const int m0 = blockIdx.x * 64;
    const int lane = t & 63;
    const int wv = t >> 6;        // wave -> 64-col quadrant of N=256
    const int m = lane & 15;
    const int quad = lane >> 4;

    // B fragments from pre-transposed W1T: vectorized 16B loads, L2-hot
    bf16x8 Bf[4][4];
    float b1v[4];
#pragma unroll
    for (int nt = 0; nt < 4; ++nt) {
        int n = wv * 64 + nt * 16 + m;
        b1v[nt] = (n >= DIM) ? b1[n - DIM] : 0.f;   // fold b1 into Q half
#pragma unroll
        for (int kt = 0; kt < 4; ++kt)
            Bf[nt][kt] = *(const bf16x8*)&W1T[(size_t)n * DIM + kt * 32 + quad * 8];
    }

    // stage A tile: 64 rows x 128 cols f32 -> bf16 LDS, swizzled 16B chunks
#pragma unroll
    for (int it = 0; it < 4; ++it) {
        int i = t + it * 256;          // 1024 chunks of 16B
        int r = i >> 4;
        int c = i & 15;
        int gr = m0 + r;
        float4 v0 = make_float4(0.f, 0.f, 0.f, 0.f), v1 = v0;
        if (gr < n_nodes) {
            const float* hp = h + (size_t)gr * DIM + c * 8;
            v0 = *(const float4*)hp;
            v1 = *(const float4*)(hp + 4);
        }
        bf16x8 o;
        o[0] = (short)f2bf(v0.x); o[1] = (short)f2bf(v0.y);
        o[2] = (short)f2bf(v0.z); o[3] = (short)f2bf(v0.w);
        o[4] = (short)f2bf(v1.x); o[5] = (short)f2bf(v1.y);
        o[6] = (short)f2bf(v1.z); o[7] = (short)f2bf(v1.w);
        int byteoff = r * 256 + ((c * 16) ^ ((r & 7) << 4));
        *(bf16x8*)((char*)Abf + byteoff) = o;
    }
    __syncthreads();

#pragma unroll
    for (int mt = 0; mt < 4; ++mt) {
        bf16x8 af[4];
        int row = mt * 16 + m;
        int rs = row * 256;
        int sw = (row & 7) << 4;
#pragma unroll
        for (int kt = 0; kt < 4; ++kt) {
            int byteoff = rs + (((kt * 4 + quad) * 16) ^ sw);
            af[kt] = *(const bf16x8*)((const char*)Abf + byteoff);
        }
#pragma unroll
        for (int nt = 0; nt < 4; ++nt) {
            f32x4 acc = {0.f, 0.f, 0.f, 0.f};
#pragma unroll
            for (int kt = 0; kt < 4; ++kt)
                acc = __builtin_amdgcn_mfma_f32_16x16x32_bf16(af[kt], Bf[nt][kt], acc, 0, 0, 0);
            int nn = wv * 64 + nt * 16 + m;   // C/D: col = lane&15, row = quad*4+r
#pragma unroll
            for (int r = 0; r < 4; ++r) {
                int crow = mt * 16 + quad * 4 + r;
                int byteoff = crow * 512 + ((nn * 2) ^ ((crow & 7) << 4));
                *(unsigned short*)((char*)Cst + byteoff) = f2bf(acc[r] + b1v[nt]);
            }
        }
    }
    __syncthreads();

    // cooperative vector store of the 64x256 bf16 tile (un-swizzle on read)
#pragma unroll
    for (int it = 0; it < 8; ++it) {
        int i = t + it * 256;          // 2048 chunks of 16B
        int r = i >> 5;
        int c = i & 31;
        int gm = m0 + r;
        if (gm < n_nodes) {
            int byteoff = r * 512 + ((c * 16) ^ ((r & 7) << 4));
            *(bf16x8*)(PQ + (size_t)gm * 256 + c * 8) =
                *(const bf16x8*)((const char*)Cst + byteoff);
        }
    }
}

// ---------------- Stage B: per-edge MLP via LDS-staged 64-edge chunks --------
__global__ __launch_bounds__(256) void edge_mlp_kernel(
    const unsigned short* __restrict__ PQ,
    const unsigned short* __restrict__ W2T,
    const float* __restrict__ b2,
    const int* __restrict__ src,
    const int* __restrict__ dst,
    float* __restrict__ out,
    int n_edges)
{
    __shared__ unsigned short hidL[64 * 128];   // 16 KB, XOR-swizzled
    __shared__ float b2s[NPAD];

    const int t = threadIdx.x;
    const int lane = t & 63;
    const int wv = t >> 6;        // wave 0..3 -> 16-edge strip
    const int m = lane & 15;
    const int quad = lane >> 4;

    if (t < NPAD) b2s[t] = (t < C_OUT) ? b2[t] : 0.f;

    // B fragments from global pre-transposed W2T (24.6 KB, L2-hot)
    bf16x8 Bfrag[6][4];
#pragma unroll
    for (int nt = 0; nt < 6; ++nt)
#pragma unroll
        for (int kt = 0; kt < 4; ++kt)
            Bfrag[nt][kt] = *(const bf16x8*)&W2T[(size_t)(nt * 16 + m) * DIM + kt * 32 + quad * 8];
    __syncthreads();   // b2s ready

    for (int e0 = blockIdx.x * 64; e0 < n_edges; e0 += gridDim.x * 64) {
        // phase 1: hid[e][k] = relu(P[src][k] + Q'[dst][k]) -> bf16 LDS
#pragma unroll
        for (int it = 0; it < 4; ++it) {
            int i = t + it * 256;     // 1024 chunks of 16B
            int e = i >> 4;
            int c = i & 15;
            int edge = e0 + e;
            bf16x8 hv;
#pragma unroll
            for (int j = 0; j < 8; ++j) hv[j] = 0;
            if (edge < n_edges) {
                int s = src[edge];
                int d = dst[edge];
                bf16x8 pv = *(const bf16x8*)(PQ + (size_t)s * 256 + c * 8);
                bf16x8 qv = *(const bf16x8*)(PQ + (size_t)d * 256 + 128 + c * 8);
#pragma unroll
                for (int j = 0; j < 8; ++j) {
                    float x = bf2f((unsigned short)pv[j]) + bf2f((unsigned short)qv[j]);
                    hv[j] = (short)f2bf(fmaxf(x, 0.f));
                }
            }
            *(bf16x8*)((char*)hidL + e * 256 + ((c * 16) ^ ((e & 7) << 4))) = hv;
        }
        __syncthreads();

        // phase 2: 16 edges x 96 cols per wave, K=128 in 4 MFMA steps
        bf16x8 af[4];
        {
            int row = wv * 16 + m;
            int rs = row * 256;
            int sw = (row & 7) << 4;
#pragma unroll
            for (int kt = 0; kt < 4; ++kt) {
                int byteoff = rs + (((kt * 4 + quad) * 16) ^ sw);
                af[kt] = *(const bf16x8*)((const char*)hidL + byteoff);
            }
        }
#pragma unroll
        for (int nt = 0; nt < 6; ++nt) {
            f32x4 acc = {0.f, 0.f, 0.f, 0.f};
#pragma unroll
            for (int kt = 0; kt < 4; ++kt)
                acc = __builtin_amdgcn_mfma_f32_16x16x32_bf16(af[kt], Bfrag[nt][kt], acc, 0, 0, 0);
            int col = nt * 16 + m;   // C/D: col = lane&15, row = quad*4 + reg
            if (col < C_OUT) {
                float bias = b2s[col];
                int ebase = e0 + wv * 16 + quad * 4;
#pragma unroll
                for (int r = 0; r < 4; ++r) {
                    int e2 = ebase + r;
                    if (e2 < n_edges)
                        out[(size_t)e2 * C_OUT + col] = acc[r] + bias;
                }
            }
        }
        __syncthreads();   // protect hidL before next chunk overwrites
    }
}

extern "C" void kernel_launch(void* const* d_in, const int* in_sizes, int n_in,
                              void* d_out, int out_size, void* d_ws, size_t ws_size,
                              hipStream_t stream) {
    const float* h  = (const float*)d_in[0];
    const float* W1 = (const float*)d_in[1];
    const float* b1 = (const float*)d_in[2];
    const float* W2 = (const float*)d_in[3];
    const float* b2 = (const float*)d_in[4];
    const int* src  = (const int*)d_in[5];
    const int* dst  = (const int*)d_in[6];
    float* out = (float*)d_out;
    const int n_nodes = in_sizes[0] / DIM;      // 100000
    const int n_edges = in_sizes[5];            // 1000000

    // workspace layout: W1T (64 KB) | W2T (24 KB) | PQ (51.2 MB)
    unsigned short* W1T = (unsigned short*)d_ws;
    unsigned short* W2T = W1T + 256 * DIM;
    unsigned short* PQ  = W2T + NPAD * DIM;

    setup_kernel<<<dim3((256 * DIM + NPAD * DIM + 255) / 256), 256, 0, stream>>>(W1, W2, W1T, W2T);
    node_gemm_kernel<<<dim3((n_nodes + 63) / 64), 256, 0, stream>>>(h, W1T, b1, PQ, n_nodes);
    edge_mlp_kernel<<<dim3(2048), 256, 0, stream>>>(PQ, W2T, b2, src, dst, out, n_edges);
}